// Round 9
// baseline (282.628 us; speedup 1.0000x reference)
//
#include <hip/hip_runtime.h>

#define B_ 512
#define L_ 512
#define N_ 128
#define TM 256          // boundary: fwd produces alpha_255, bwd produces beta_255
#define C_BIAS 3.0f

typedef float f4_t __attribute__((ext_vector_type(4)));
typedef int   v8i_t __attribute__((ext_vector_type(8)));

// ---- full-rate VALU wave-64 reductions via DPP (no ds_swizzle chains) ----
#define DPP_STEP_MAX(v, ctrl)                                                   \
    {                                                                           \
        int _t = __builtin_amdgcn_update_dpp(__float_as_int(v),                 \
                    __float_as_int(v), ctrl, 0xf, 0xf, false);                  \
        v = fmaxf(v, __int_as_float(_t));                                       \
    }
#define DPP_STEP_ADD(v, ctrl)                                                   \
    {                                                                           \
        int _t = __builtin_amdgcn_update_dpp(__float_as_int(v),                 \
                    __float_as_int(v), ctrl, 0xf, 0xf, false);                  \
        v = v + __int_as_float(_t);                                             \
    }

__device__ __forceinline__ float wave_max(float v) {
    DPP_STEP_MAX(v, 0xB1);   // quad_perm [1,0,3,2]
    DPP_STEP_MAX(v, 0x4E);   // quad_perm [2,3,0,1]
    DPP_STEP_MAX(v, 0x141);  // row_half_mirror
    DPP_STEP_MAX(v, 0x140);  // row_mirror
    DPP_STEP_MAX(v, 0x142);  // row_bcast15
    DPP_STEP_MAX(v, 0x143);  // row_bcast31
    return __int_as_float(__builtin_amdgcn_readlane(__float_as_int(v), 63));
}
__device__ __forceinline__ float wave_sum(float v) {
    DPP_STEP_ADD(v, 0xB1);
    DPP_STEP_ADD(v, 0x4E);
    DPP_STEP_ADD(v, 0x141);
    DPP_STEP_ADD(v, 0x140);
    DPP_STEP_ADD(v, 0x142);  // lane63 path stays exact; other lanes don't matter
    DPP_STEP_ADD(v, 0x143);
    return __int_as_float(__builtin_amdgcn_readlane(__float_as_int(v), 63));
}

// ---- fp8 (OCP e4m3fn) packing helpers ----
#if __has_builtin(__builtin_amdgcn_cvt_pk_fp8_f32)
__device__ __forceinline__ unsigned fp8_pair(float a, float b) {
    // byte0 = fp8(a), byte1 = fp8(b) in word0
    return (unsigned)__builtin_amdgcn_cvt_pk_fp8_f32(a, b, 0, false);
}
__device__ __forceinline__ unsigned fp8_quad(float a, float b, float c, float d) {
    int lo = __builtin_amdgcn_cvt_pk_fp8_f32(a, b, 0, false);
    return (unsigned)__builtin_amdgcn_cvt_pk_fp8_f32(c, d, lo, true);
}
#else
__device__ __forceinline__ unsigned char f32_e4m3(float v) {
    if (!(v > 0.f)) return 0;                 // inputs here are always >= 0
    if (v >= 448.f) return 0x7E;              // clamp to max finite
    if (v < 0.015625f) {                      // denormal grid: m * 2^-9
        int m = (int)(v * 512.f + 0.5f);
        return (unsigned char)m;              // m==8 rolls into first normal: ok
    }
    union { float f; unsigned u; } x; x.f = v;
    unsigned u = x.u;
    unsigned lsb = (u >> 20) & 1;
    u += 0x0007FFFF + lsb;                    // RNE to 3 mantissa bits
    int e = (int)((u >> 23) & 255) - 127 + 7; // rebias to e4
    unsigned m = (u >> 20) & 7;
    if (e > 15) return 0x7E;
    return (unsigned char)((e << 3) | m);
}
__device__ __forceinline__ unsigned fp8_pair(float a, float b) {
    return (unsigned)f32_e4m3(a) | ((unsigned)f32_e4m3(b) << 8);
}
__device__ __forceinline__ unsigned fp8_quad(float a, float b, float c, float d) {
    return fp8_pair(a, b) | (fp8_pair(c, d) << 16);
}
#endif

#define SCALE_ONE 0x7F7F7F7F   // every e8m0 byte = 2^0: scale-layout-proof

// One j-tile: FULL K=128 contraction in a single MX MFMA.
#define MXMFMA(qv, bt)                                                          \
    f4_t qv = __builtin_amdgcn_mfma_scale_f32_16x16x128_f8f6f4(                 \
        Afrag, bt, z, 0, 0, 0, SCALE_ONE, 0, SCALE_ONE);

// ---------------------------------------------------------------------------
// norm_kernel: 1024 blocks x 64 threads (1 wave) = 1 wave/SIMD. Per step the
// 128-wide LSE matvec = 8x mfma_scale_f32_16x16x128_f8f6f4 (R7 structure),
// sigma-permuted E layout + early A-read (R8).
// R9: ALGEBRAIC BYPASS of log->exp on the E critical path. Since
//   exp(nxt - mx - C) = S * exp(em + Mprev - mx)   [the C and log cancel],
// the written E needs NO transcendental after the MFMA: W = exp(em+Mprev-mx)
// and the mask-0 candidate exp(ns_old - mx - C) are computed DURING the MFMA
// phase (inputs ready at step start). Post-MFMA chain: pickup -> mul ->
// cndmask -> cvt_pk -> ds_write -> ds_read. The state path (__logf + blend),
// needed only next step, is placed after the Af read behind a sched_barrier
// so the scheduler cannot hoist the quarter-rate logs onto the store path.
// Mask is exactly {0,1} (all-ones here): blend == select, algebra exact.
// Lane l owns states s0 = 32*(l>>4) + (l&15), s1 = s0+16; in-register pickup
// from replicated D rows; lagged DPP max + C_BIAS=3 keeps E <= ~e^5 << 448.
// ---------------------------------------------------------------------------
__global__ __launch_bounds__(64, 1) void norm_kernel(
    const float* __restrict__ em, const int* __restrict__ tg,
    const float* __restrict__ mask, const float* __restrict__ st,
    const float* __restrict__ trans,
    float* __restrict__ alpha, float* __restrict__ beta,
    float* __restrict__ pathf, float* __restrict__ pathb)
{
    __shared__ __align__(32) unsigned char Eh[128];  // E/F vector, fp8, sigma layout
    __shared__ float Mlds[TM];                       // mask row half

    const int l  = threadIdx.x;
    const int c  = l & 15;       // MFMA n-index (D col)
    const int h  = l >> 4;       // MFMA k-group (32 bytes per group)
    const int s0 = 32 * h + c;   // owned state 0  (j-tile 2h)
    const int s1 = s0 + 16;      // owned state 1  (j-tile 2h+1)
    const bool hb0 = (h & 1) != 0;
    const bool hb1 = (h & 2) != 0;
    const int b  = blockIdx.x >> 1;
    const int bw = blockIdx.x & 1;
    const size_t base = (size_t)b * L_ * N_;
    const int bL = b * L_;

    if (bw == 0) {
        // ================= FORWARD =================
        // path-score half: t in [1, TM)
        float pacc = 0.f;
        for (int t = 1 + l; t < TM; t += 64) {
            int cur  = tg[bL + t];
            int prev = tg[bL + t - 1];
            pacc += mask[bL + t] * (trans[prev * N_ + cur] + em[base + (size_t)t * N_ + cur]);
        }
        pacc = wave_sum(pacc);
        if (l == 0) {
            int t0 = tg[bL];
            pathf[b] = pacc + st[t0] + em[base + t0];
        }

#pragma unroll
        for (int k = 0; k < 4; ++k) Mlds[l + 64 * k] = mask[bL + l + 64 * k];

        // B-fragments, sigma-permuted: byte e of k-group h = state
        // sigma(h,e) = 32h + (e>>1) + 16*(e&1). Quad dd covers states
        // {32h+2dd, 32h+16+2dd, 32h+2dd+1, 32h+17+2dd} (cols j = 16jt + c).
        v8i_t Bf[8];
#pragma unroll
        for (int jt = 0; jt < 8; ++jt) {
            v8i_t bb;
#pragma unroll
            for (int dd = 0; dd < 8; ++dd) {
                const float* p = trans + (size_t)(32 * h + 2 * dd) * N_ + 16 * jt + c;
                float f0 = __expf(p[0]);           // state 32h+2dd
                float f1 = __expf(p[16 * N_]);     // state 32h+16+2dd
                float f2 = __expf(p[N_]);          // state 32h+2dd+1
                float f3 = __expf(p[17 * N_]);     // state 32h+17+2dd
                bb[dd] = (int)fp8_quad(f0, f1, f2, f3);
            }
            Bf[jt] = bb;
        }

        // init alpha_0
        float ns0 = st[s0] + em[base + s0];
        float ns1 = st[s1] + em[base + s1];
        float Mprev = wave_max(fmaxf(ns0, ns1));
        {
            unsigned p = fp8_pair(__expf(ns0 - Mprev - C_BIAS), __expf(ns1 - Mprev - C_BIAS));
            *(unsigned short*)(Eh + 2 * l) = (unsigned short)p;
        }
        v8i_t Af = *(const v8i_t*)(Eh + 32 * h);   // A-frag for step 1

        float pa0 = em[base + (size_t)1 * N_ + s0], pb0 = em[base + (size_t)1 * N_ + s1];
        float pa1 = em[base + (size_t)2 * N_ + s0], pb1 = em[base + (size_t)2 * N_ + s1];
        float pa2 = em[base + (size_t)3 * N_ + s0], pb2 = em[base + (size_t)3 * N_ + s1];
        float pa3 = em[base + (size_t)4 * N_ + s0], pb3 = em[base + (size_t)4 * N_ + s1];

        auto step = [&](int t, float& sa, float& sb) {
            float emv0 = sa, emv1 = sb;
            int tpf = t + 4; if (tpf > TM - 1) tpf = TM - 1;
            sa = em[base + (size_t)tpf * N_ + s0];
            sb = em[base + (size_t)tpf * N_ + s1];
            float mk = Mlds[t];

            float mx = wave_max(fmaxf(ns0, ns1));   // max(ns_{t-1})

            // off-critical precompute: hides under the MFMA phase
            float W0  = __expf(emv0 + Mprev - mx);           // mask=1: E = S*W
            float W1  = __expf(emv1 + Mprev - mx);
            float E00 = __expf(ns0 - mx - C_BIAS);           // mask=0 candidate
            float E01 = __expf(ns1 - mx - C_BIAS);

            v8i_t Afrag = Af;                       // carried early read
            f4_t z = {0.f, 0.f, 0.f, 0.f};
            MXMFMA(q0, Bf[0]) MXMFMA(q1, Bf[1]) MXMFMA(q2, Bf[2]) MXMFMA(q3, Bf[3])
            MXMFMA(q4, Bf[4]) MXMFMA(q5, Bf[5]) MXMFMA(q6, Bf[6]) MXMFMA(q7, Bf[7])

            // in-register pickup of owned states (replicated D rows, reg 0)
            float sv0 = hb1 ? (hb0 ? q6[0] : q4[0]) : (hb0 ? q2[0] : q0[0]);
            float sv1 = hb1 ? (hb0 ? q7[0] : q5[0]) : (hb0 ? q3[0] : q1[0]);

            // E critical path: mul + select + pack + write + read (no trans!)
            bool mc = (mk != 0.0f);
            float Ef0 = mc ? (sv0 * W0) : E00;
            float Ef1 = mc ? (sv1 * W1) : E01;
            unsigned p = fp8_pair(Ef0, Ef1);
            *(unsigned short*)(Eh + 2 * l) = (unsigned short)p;
            Af = *(const v8i_t*)(Eh + 32 * h);      // early read for step t+1
            __builtin_amdgcn_sched_barrier(0);      // keep logs off the store path

            // state path (consumed next step)
            float badd = Mprev + C_BIAS;
            float nxt0 = __logf(sv0) + badd + emv0;
            float nxt1 = __logf(sv1) + badd + emv1;
            float im = 1.f - mk;
            ns0 = mk * nxt0 + im * ns0;
            ns1 = mk * nxt1 + im * ns1;
            Mprev = mx;
        };

        for (int tt = 1; tt + 3 < TM; tt += 4) {
            step(tt    , pa0, pb0);
            step(tt + 1, pa1, pb1);
            step(tt + 2, pa2, pb2);
            step(tt + 3, pa3, pb3);
        }
        step(TM - 3, pa0, pb0);
        step(TM - 2, pa1, pb1);
        step(TM - 1, pa2, pb2);

        alpha[b * N_ + s0] = ns0;
        alpha[b * N_ + s1] = ns1;
    } else {
        // ================= BACKWARD =================
        // path-score half: t in [TM, L)
        float pacc = 0.f;
        for (int t = TM + l; t < L_; t += 64) {
            int cur  = tg[bL + t];
            int prev = tg[bL + t - 1];
            pacc += mask[bL + t] * (trans[prev * N_ + cur] + em[base + (size_t)t * N_ + cur]);
        }
        pacc = wave_sum(pacc);
        if (l == 0) pathb[b] = pacc;

#pragma unroll
        for (int k = 0; k < 4; ++k) Mlds[l + 64 * k] = mask[bL + TM + l + 64 * k];

        // B-fragments, sigma-permuted: byte e = exp(trans[16it + c][sigma(h,e)])
        v8i_t Bf[8];
#pragma unroll
        for (int it = 0; it < 8; ++it) {
            v8i_t bb;
#pragma unroll
            for (int dd = 0; dd < 8; ++dd) {
                const float* p = trans + (size_t)(16 * it + c) * N_ + 32 * h + 2 * dd;
                float f0 = __expf(p[0]);    // col 32h+2dd
                float f1 = __expf(p[16]);   // col 32h+16+2dd
                float f2 = __expf(p[1]);    // col 32h+2dd+1
                float f3 = __expf(p[17]);   // col 32h+17+2dd
                bb[dd] = (int)fp8_quad(f0, f1, f2, f3);
            }
            Bf[it] = bb;
        }

        // init at u=511: beta_511 = 0 ; v = beta + em_511
        float b0 = 0.f, b1 = 0.f;
        float v0 = em[base + (size_t)(L_ - 1) * N_ + s0];
        float v1 = em[base + (size_t)(L_ - 1) * N_ + s1];
        float Mprev = wave_max(fmaxf(v0, v1));
        {
            unsigned p = fp8_pair(__expf(v0 - Mprev - C_BIAS), __expf(v1 - Mprev - C_BIAS));
            *(unsigned short*)(Eh + 2 * l) = (unsigned short)p;
        }
        v8i_t Af = *(const v8i_t*)(Eh + 32 * h);

        float pa0 = em[base + (size_t)510 * N_ + s0], pb0 = em[base + (size_t)510 * N_ + s1];
        float pa1 = em[base + (size_t)509 * N_ + s0], pb1 = em[base + (size_t)509 * N_ + s1];
        float pa2 = em[base + (size_t)508 * N_ + s0], pb2 = em[base + (size_t)508 * N_ + s1];
        float pa3 = em[base + (size_t)507 * N_ + s0], pb3 = em[base + (size_t)507 * N_ + s1];

        // iter t (510 down to 255): consumes F_{t+1} (Eh), em_t (pipe), mask_{t+1}
        auto step = [&](int t, float& sa, float& sb) {
            float emt0 = sa, emt1 = sb;
            int tpf = t - 4; if (tpf < TM - 1) tpf = TM - 1;
            sa = em[base + (size_t)tpf * N_ + s0];
            sb = em[base + (size_t)tpf * N_ + s1];
            float mk = Mlds[t + 1 - TM];

            float mx = wave_max(fmaxf(v0, v1));   // max(v_{t+1})

            // off-critical precompute (hides under MFMA):
            // mask=1: F = exp(log S + Mprev + C + em - mx - C) = S*exp(em+Mprev-mx)
            float W0  = __expf(emt0 + Mprev - mx);
            float W1  = __expf(emt1 + Mprev - mx);
            // mask=0: F = exp(b_old + em_t - mx - C)
            float F00 = __expf(b0 + emt0 - mx - C_BIAS);
            float F01 = __expf(b1 + emt1 - mx - C_BIAS);

            v8i_t Afrag = Af;                     // carried early read
            f4_t z = {0.f, 0.f, 0.f, 0.f};
            MXMFMA(q0, Bf[0]) MXMFMA(q1, Bf[1]) MXMFMA(q2, Bf[2]) MXMFMA(q3, Bf[3])
            MXMFMA(q4, Bf[4]) MXMFMA(q5, Bf[5]) MXMFMA(q6, Bf[6]) MXMFMA(q7, Bf[7])

            float sv0 = hb1 ? (hb0 ? q6[0] : q4[0]) : (hb0 ? q2[0] : q0[0]);
            float sv1 = hb1 ? (hb0 ? q7[0] : q5[0]) : (hb0 ? q3[0] : q1[0]);

            // F critical path: mul + select + pack + write + read (no trans!)
            bool mc = (mk != 0.0f);
            float Ff0 = mc ? (sv0 * W0) : F00;
            float Ff1 = mc ? (sv1 * W1) : F01;
            unsigned p = fp8_pair(Ff0, Ff1);
            *(unsigned short*)(Eh + 2 * l) = (unsigned short)p;
            Af = *(const v8i_t*)(Eh + 32 * h);    // early read for next step
            __builtin_amdgcn_sched_barrier(0);    // keep logs off the store path

            // state path (consumed next step)
            float badd = Mprev + C_BIAS;
            float upd0 = __logf(sv0) + badd;
            float upd1 = __logf(sv1) + badd;
            float im = 1.f - mk;
            b0 = mk * upd0 + im * b0;
            b1 = mk * upd1 + im * b1;
            v0 = b0 + emt0;
            v1 = b1 + emt1;
            Mprev = mx;
        };

        for (int tt = 510; tt >= 258; tt -= 4) {   // 64 groups x 4 = t 510..255
            step(tt    , pa0, pb0);
            step(tt - 1, pa1, pb1);
            step(tt - 2, pa2, pb2);
            step(tt - 3, pa3, pb3);
        }

        beta[b * N_ + s0] = b0;
        beta[b * N_ + s1] = b1;
    }
}

// ---------------------------------------------------------------------------
// zres_kernel: 512 blocks x 1 wave. Block b: zres[b] = LSE_j(alpha[j]+beta[j])
//              - pathf[b] - pathb[b].
// ---------------------------------------------------------------------------
__global__ __launch_bounds__(64) void zres_kernel(
    const float* __restrict__ alpha, const float* __restrict__ beta,
    const float* __restrict__ pathf, const float* __restrict__ pathb,
    float* __restrict__ zres)
{
    const int l = threadIdx.x;
    const int b = blockIdx.x;
    float2 av = *(const float2*)(alpha + b * N_ + 2 * l);
    float2 bv = *(const float2*)(beta  + b * N_ + 2 * l);
    float v0 = av.x + bv.x;
    float v1 = av.y + bv.y;
    float m = wave_max(fmaxf(v0, v1));
    float s = wave_sum(__expf(v0 - m) + __expf(v1 - m));
    if (l == 0) zres[b] = m + __logf(s) - pathf[b] - pathb[b];
}

// ---------------------------------------------------------------------------
// mean_kernel: 1 wave. out = mean(zres). 8 values/lane (2x float4) + DPP tree.
// ---------------------------------------------------------------------------
__global__ __launch_bounds__(64) void mean_kernel(
    const float* __restrict__ zres, float* __restrict__ out)
{
    const int l = threadIdx.x;
    const float4* z4 = (const float4*)zres;
    float4 a = z4[2 * l];
    float4 c = z4[2 * l + 1];
    float acc = ((a.x + a.y) + (a.z + a.w)) + ((c.x + c.y) + (c.z + c.w));
    acc = wave_sum(acc);
    if (l == 0) out[0] = acc * (1.0f / (float)B_);
}

// ---------------------------------------------------------------------------
extern "C" void kernel_launch(void* const* d_in, const int* in_sizes, int n_in,
                              void* d_out, int out_size, void* d_ws, size_t ws_size,
                              hipStream_t stream) {
    const float* emission    = (const float*)d_in[0];
    const int*   target      = (const int*)  d_in[1];
    const float* mask        = (const float*)d_in[2];
    const float* start_trans = (const float*)d_in[3];
    const float* trans       = (const float*)d_in[4];
    float* out = (float*)d_out;

    float* ws_f  = (float*)d_ws;
    float* alpha = ws_f;                        // 512*128
    float* beta  = ws_f + B_ * N_;              // 512*128
    float* pathf = ws_f + 2 * B_ * N_;          // 512
    float* pathb = ws_f + 2 * B_ * N_ + B_;     // 512
    float* zres  = ws_f + 2 * B_ * N_ + 2 * B_; // 512

    norm_kernel<<<2 * B_, 64, 0, stream>>>(emission, target, mask, start_trans,
                                           trans, alpha, beta, pathf, pathb);
    zres_kernel<<<B_, 64, 0, stream>>>(alpha, beta, pathf, pathb, zres);
    mean_kernel<<<1, 64, 0, stream>>>(zres, out);
}

// Round 10
// 280.057 us; speedup vs baseline: 1.0092x; 1.0092x over previous
//
#include <hip/hip_runtime.h>

#define B_ 512
#define L_ 512
#define N_ 128
#define TM 256          // boundary: fwd produces alpha_255, bwd produces beta_255
#define C_BIAS 3.0f

typedef float f4_t __attribute__((ext_vector_type(4)));
typedef int   v8i_t __attribute__((ext_vector_type(8)));

// ---- full-rate VALU wave-64 reductions via DPP (no ds_swizzle chains) ----
#define DPP_STEP_MAX(v, ctrl)                                                   \
    {                                                                           \
        int _t = __builtin_amdgcn_update_dpp(__float_as_int(v),                 \
                    __float_as_int(v), ctrl, 0xf, 0xf, false);                  \
        v = fmaxf(v, __int_as_float(_t));                                       \
    }
#define DPP_STEP_ADD(v, ctrl)                                                   \
    {                                                                           \
        int _t = __builtin_amdgcn_update_dpp(__float_as_int(v),                 \
                    __float_as_int(v), ctrl, 0xf, 0xf, false);                  \
        v = v + __int_as_float(_t);                                             \
    }

__device__ __forceinline__ float wave_max(float v) {
    DPP_STEP_MAX(v, 0xB1);   // quad_perm [1,0,3,2]
    DPP_STEP_MAX(v, 0x4E);   // quad_perm [2,3,0,1]
    DPP_STEP_MAX(v, 0x141);  // row_half_mirror
    DPP_STEP_MAX(v, 0x140);  // row_mirror
    DPP_STEP_MAX(v, 0x142);  // row_bcast15
    DPP_STEP_MAX(v, 0x143);  // row_bcast31
    return __int_as_float(__builtin_amdgcn_readlane(__float_as_int(v), 63));
}
__device__ __forceinline__ float wave_sum(float v) {
    DPP_STEP_ADD(v, 0xB1);
    DPP_STEP_ADD(v, 0x4E);
    DPP_STEP_ADD(v, 0x141);
    DPP_STEP_ADD(v, 0x140);
    DPP_STEP_ADD(v, 0x142);  // lane63 path stays exact; other lanes don't matter
    DPP_STEP_ADD(v, 0x143);
    return __int_as_float(__builtin_amdgcn_readlane(__float_as_int(v), 63));
}

// ---- fp8 (OCP e4m3fn) packing helpers ----
#if __has_builtin(__builtin_amdgcn_cvt_pk_fp8_f32)
__device__ __forceinline__ unsigned fp8_pair(float a, float b) {
    // byte0 = fp8(a), byte1 = fp8(b) in word0
    return (unsigned)__builtin_amdgcn_cvt_pk_fp8_f32(a, b, 0, false);
}
__device__ __forceinline__ unsigned fp8_quad(float a, float b, float c, float d) {
    int lo = __builtin_amdgcn_cvt_pk_fp8_f32(a, b, 0, false);
    return (unsigned)__builtin_amdgcn_cvt_pk_fp8_f32(c, d, lo, true);
}
#else
__device__ __forceinline__ unsigned char f32_e4m3(float v) {
    if (!(v > 0.f)) return 0;                 // inputs here are always >= 0
    if (v >= 448.f) return 0x7E;              // clamp to max finite
    if (v < 0.015625f) {                      // denormal grid: m * 2^-9
        int m = (int)(v * 512.f + 0.5f);
        return (unsigned char)m;              // m==8 rolls into first normal: ok
    }
    union { float f; unsigned u; } x; x.f = v;
    unsigned u = x.u;
    unsigned lsb = (u >> 20) & 1;
    u += 0x0007FFFF + lsb;                    // RNE to 3 mantissa bits
    int e = (int)((u >> 23) & 255) - 127 + 7; // rebias to e4
    unsigned m = (u >> 20) & 7;
    if (e > 15) return 0x7E;
    return (unsigned char)((e << 3) | m);
}
__device__ __forceinline__ unsigned fp8_pair(float a, float b) {
    return (unsigned)f32_e4m3(a) | ((unsigned)f32_e4m3(b) << 8);
}
__device__ __forceinline__ unsigned fp8_quad(float a, float b, float c, float d) {
    return fp8_pair(a, b) | (fp8_pair(c, d) << 16);
}
#endif

#define SCALE_ONE 0x7F7F7F7F   // every e8m0 byte = 2^0: scale-layout-proof

// One j-tile: FULL K=128 contraction in a single MX MFMA.
#define MXMFMA(qv, bt)                                                          \
    f4_t qv = __builtin_amdgcn_mfma_scale_f32_16x16x128_f8f6f4(                 \
        Afrag, bt, z, 0, 0, 0, SCALE_ONE, 0, SCALE_ONE);

// ---------------------------------------------------------------------------
// norm_kernel: 1024 blocks x 64 threads (1 wave) = 1 wave/SIMD. Per step the
// 128-wide LSE matvec = 8x mfma_scale_f32_16x16x128_f8f6f4 (R7 structure),
// sigma-permuted E layout + early A-read (R8). MFMA blocks its wave (no
// same-wave overlap, 1 wave/SIMD): the step is a fully serial issue+latency
// chain, so R10 only REMOVES ops/latency vs R8:
//  (1) mask rides the 4-deep prefetch pipe from GLOBAL (wave-uniform
//      broadcast, ~5000 cy slack) — deletes the mid-step Mlds LDS read
//      (~60-120 cy single-outstanding latency) and the staging loop.
//  (2) badd+em folded into one pre-MFMA add: post-MFMA chain is
//      pickup -> log -> +pre -> blend -> exp -> pack -> write -> read.
// Lane l owns states s0 = 32*(l>>4) + (l&15), s1 = s0+16; in-register pickup
// from replicated D rows; lagged DPP max + C_BIAS=3 keeps E <= ~e^5 << 448.
// ---------------------------------------------------------------------------
__global__ __launch_bounds__(64, 1) void norm_kernel(
    const float* __restrict__ em, const int* __restrict__ tg,
    const float* __restrict__ mask, const float* __restrict__ st,
    const float* __restrict__ trans,
    float* __restrict__ alpha, float* __restrict__ beta,
    float* __restrict__ pathf, float* __restrict__ pathb)
{
    __shared__ __align__(32) unsigned char Eh[128];  // E/F vector, fp8, sigma layout

    const int l  = threadIdx.x;
    const int c  = l & 15;       // MFMA n-index (D col)
    const int h  = l >> 4;       // MFMA k-group (32 bytes per group)
    const int s0 = 32 * h + c;   // owned state 0  (j-tile 2h)
    const int s1 = s0 + 16;      // owned state 1  (j-tile 2h+1)
    const bool hb0 = (h & 1) != 0;
    const bool hb1 = (h & 2) != 0;
    const int b  = blockIdx.x >> 1;
    const int bw = blockIdx.x & 1;
    const size_t base = (size_t)b * L_ * N_;
    const int bL = b * L_;

    if (bw == 0) {
        // ================= FORWARD =================
        // path-score half: t in [1, TM)
        float pacc = 0.f;
        for (int t = 1 + l; t < TM; t += 64) {
            int cur  = tg[bL + t];
            int prev = tg[bL + t - 1];
            pacc += mask[bL + t] * (trans[prev * N_ + cur] + em[base + (size_t)t * N_ + cur]);
        }
        pacc = wave_sum(pacc);
        if (l == 0) {
            int t0 = tg[bL];
            pathf[b] = pacc + st[t0] + em[base + t0];
        }

        // B-fragments, sigma-permuted: byte e of k-group h = state
        // sigma(h,e) = 32h + (e>>1) + 16*(e&1). Quad dd covers states
        // {32h+2dd, 32h+16+2dd, 32h+2dd+1, 32h+17+2dd} (cols j = 16jt + c).
        v8i_t Bf[8];
#pragma unroll
        for (int jt = 0; jt < 8; ++jt) {
            v8i_t bb;
#pragma unroll
            for (int dd = 0; dd < 8; ++dd) {
                const float* p = trans + (size_t)(32 * h + 2 * dd) * N_ + 16 * jt + c;
                float f0 = __expf(p[0]);           // state 32h+2dd
                float f1 = __expf(p[16 * N_]);     // state 32h+16+2dd
                float f2 = __expf(p[N_]);          // state 32h+2dd+1
                float f3 = __expf(p[17 * N_]);     // state 32h+17+2dd
                bb[dd] = (int)fp8_quad(f0, f1, f2, f3);
            }
            Bf[jt] = bb;
        }

        // init alpha_0
        float ns0 = st[s0] + em[base + s0];
        float ns1 = st[s1] + em[base + s1];
        float Mprev = wave_max(fmaxf(ns0, ns1));
        {
            unsigned p = fp8_pair(__expf(ns0 - Mprev - C_BIAS), __expf(ns1 - Mprev - C_BIAS));
            *(unsigned short*)(Eh + 2 * l) = (unsigned short)p;
        }
        v8i_t Af = *(const v8i_t*)(Eh + 32 * h);   // A-frag for step 1

        float pa0 = em[base + (size_t)1 * N_ + s0], pb0 = em[base + (size_t)1 * N_ + s1];
        float pa1 = em[base + (size_t)2 * N_ + s0], pb1 = em[base + (size_t)2 * N_ + s1];
        float pa2 = em[base + (size_t)3 * N_ + s0], pb2 = em[base + (size_t)3 * N_ + s1];
        float pa3 = em[base + (size_t)4 * N_ + s0], pb3 = em[base + (size_t)4 * N_ + s1];
        float pm0 = mask[bL + 1], pm1 = mask[bL + 2];
        float pm2 = mask[bL + 3], pm3 = mask[bL + 4];

        auto step = [&](int t, float& sa, float& sb, float& sm) {
            float emv0 = sa, emv1 = sb;
            float mk = sm;
            int tpf = t + 4; if (tpf > TM - 1) tpf = TM - 1;
            sa = em[base + (size_t)tpf * N_ + s0];
            sb = em[base + (size_t)tpf * N_ + s1];
            sm = mask[bL + tpf];

            float mx = wave_max(fmaxf(ns0, ns1));   // max(ns_{t-1})
            float badd = Mprev + C_BIAS;
            float pre0 = badd + emv0;               // pre-MFMA fold
            float pre1 = badd + emv1;

            v8i_t Afrag = Af;                       // carried early read
            f4_t z = {0.f, 0.f, 0.f, 0.f};
            MXMFMA(q0, Bf[0]) MXMFMA(q1, Bf[1]) MXMFMA(q2, Bf[2]) MXMFMA(q3, Bf[3])
            MXMFMA(q4, Bf[4]) MXMFMA(q5, Bf[5]) MXMFMA(q6, Bf[6]) MXMFMA(q7, Bf[7])

            // in-register pickup of owned states (replicated D rows, reg 0)
            float sv0 = hb1 ? (hb0 ? q6[0] : q4[0]) : (hb0 ? q2[0] : q0[0]);
            float sv1 = hb1 ? (hb0 ? q7[0] : q5[0]) : (hb0 ? q3[0] : q1[0]);

            float nxt0 = __logf(sv0) + pre0;
            float nxt1 = __logf(sv1) + pre1;
            float im = 1.f - mk;
            ns0 = mk * nxt0 + im * ns0;
            ns1 = mk * nxt1 + im * ns1;

            Mprev = mx;
            unsigned p = fp8_pair(__expf(ns0 - mx - C_BIAS), __expf(ns1 - mx - C_BIAS));
            *(unsigned short*)(Eh + 2 * l) = (unsigned short)p;
            Af = *(const v8i_t*)(Eh + 32 * h);      // early read for step t+1
        };

        for (int tt = 1; tt + 3 < TM; tt += 4) {
            step(tt    , pa0, pb0, pm0);
            step(tt + 1, pa1, pb1, pm1);
            step(tt + 2, pa2, pb2, pm2);
            step(tt + 3, pa3, pb3, pm3);
        }
        step(TM - 3, pa0, pb0, pm0);
        step(TM - 2, pa1, pb1, pm1);
        step(TM - 1, pa2, pb2, pm2);

        alpha[b * N_ + s0] = ns0;
        alpha[b * N_ + s1] = ns1;
    } else {
        // ================= BACKWARD =================
        // path-score half: t in [TM, L)
        float pacc = 0.f;
        for (int t = TM + l; t < L_; t += 64) {
            int cur  = tg[bL + t];
            int prev = tg[bL + t - 1];
            pacc += mask[bL + t] * (trans[prev * N_ + cur] + em[base + (size_t)t * N_ + cur]);
        }
        pacc = wave_sum(pacc);
        if (l == 0) pathb[b] = pacc;

        // B-fragments, sigma-permuted: byte e = exp(trans[16it + c][sigma(h,e)])
        v8i_t Bf[8];
#pragma unroll
        for (int it = 0; it < 8; ++it) {
            v8i_t bb;
#pragma unroll
            for (int dd = 0; dd < 8; ++dd) {
                const float* p = trans + (size_t)(16 * it + c) * N_ + 32 * h + 2 * dd;
                float f0 = __expf(p[0]);    // col 32h+2dd
                float f1 = __expf(p[16]);   // col 32h+16+2dd
                float f2 = __expf(p[1]);    // col 32h+2dd+1
                float f3 = __expf(p[17]);   // col 32h+17+2dd
                bb[dd] = (int)fp8_quad(f0, f1, f2, f3);
            }
            Bf[it] = bb;
        }

        // init at u=511: beta_511 = 0 ; v = beta + em_511
        float b0 = 0.f, b1 = 0.f;
        float v0 = em[base + (size_t)(L_ - 1) * N_ + s0];
        float v1 = em[base + (size_t)(L_ - 1) * N_ + s1];
        float Mprev = wave_max(fmaxf(v0, v1));
        {
            unsigned p = fp8_pair(__expf(v0 - Mprev - C_BIAS), __expf(v1 - Mprev - C_BIAS));
            *(unsigned short*)(Eh + 2 * l) = (unsigned short)p;
        }
        v8i_t Af = *(const v8i_t*)(Eh + 32 * h);

        float pa0 = em[base + (size_t)510 * N_ + s0], pb0 = em[base + (size_t)510 * N_ + s1];
        float pa1 = em[base + (size_t)509 * N_ + s0], pb1 = em[base + (size_t)509 * N_ + s1];
        float pa2 = em[base + (size_t)508 * N_ + s0], pb2 = em[base + (size_t)508 * N_ + s1];
        float pa3 = em[base + (size_t)507 * N_ + s0], pb3 = em[base + (size_t)507 * N_ + s1];
        float pm0 = mask[bL + 511], pm1 = mask[bL + 510];
        float pm2 = mask[bL + 509], pm3 = mask[bL + 508];

        // iter t (510 down to 255): consumes F_{t+1} (Eh), em_t (pipe), mask_{t+1}
        auto step = [&](int t, float& sa, float& sb, float& sm) {
            float emt0 = sa, emt1 = sb;
            float mk = sm;
            int tpf = t - 4; if (tpf < TM - 1) tpf = TM - 1;
            sa = em[base + (size_t)tpf * N_ + s0];
            sb = em[base + (size_t)tpf * N_ + s1];
            sm = mask[bL + tpf + 1];

            float mx = wave_max(fmaxf(v0, v1));   // max(v_{t+1})
            float badd = Mprev + C_BIAS;

            v8i_t Afrag = Af;                     // carried early read
            f4_t z = {0.f, 0.f, 0.f, 0.f};
            MXMFMA(q0, Bf[0]) MXMFMA(q1, Bf[1]) MXMFMA(q2, Bf[2]) MXMFMA(q3, Bf[3])
            MXMFMA(q4, Bf[4]) MXMFMA(q5, Bf[5]) MXMFMA(q6, Bf[6]) MXMFMA(q7, Bf[7])

            float sv0 = hb1 ? (hb0 ? q6[0] : q4[0]) : (hb0 ? q2[0] : q0[0]);
            float sv1 = hb1 ? (hb0 ? q7[0] : q5[0]) : (hb0 ? q3[0] : q1[0]);

            float upd0 = __logf(sv0) + badd;
            float upd1 = __logf(sv1) + badd;
            float im = 1.f - mk;
            b0 = mk * upd0 + im * b0;
            b1 = mk * upd1 + im * b1;

            v0 = b0 + emt0;
            v1 = b1 + emt1;
            Mprev = mx;
            unsigned p = fp8_pair(__expf(v0 - mx - C_BIAS), __expf(v1 - mx - C_BIAS));
            *(unsigned short*)(Eh + 2 * l) = (unsigned short)p;
            Af = *(const v8i_t*)(Eh + 32 * h);    // early read for next step
        };

        for (int tt = 510; tt >= 258; tt -= 4) {   // 64 groups x 4 = t 510..255
            step(tt    , pa0, pb0, pm0);
            step(tt - 1, pa1, pb1, pm1);
            step(tt - 2, pa2, pb2, pm2);
            step(tt - 3, pa3, pb3, pm3);
        }

        beta[b * N_ + s0] = b0;
        beta[b * N_ + s1] = b1;
    }
}

// ---------------------------------------------------------------------------
// zres_kernel: 512 blocks x 1 wave. Block b: zres[b] = LSE_j(alpha[j]+beta[j])
//              - pathf[b] - pathb[b].
// ---------------------------------------------------------------------------
__global__ __launch_bounds__(64) void zres_kernel(
    const float* __restrict__ alpha, const float* __restrict__ beta,
    const float* __restrict__ pathf, const float* __restrict__ pathb,
    float* __restrict__ zres)
{
    const int l = threadIdx.x;
    const int b = blockIdx.x;
    float2 av = *(const float2*)(alpha + b * N_ + 2 * l);
    float2 bv = *(const float2*)(beta  + b * N_ + 2 * l);
    float v0 = av.x + bv.x;
    float v1 = av.y + bv.y;
    float m = wave_max(fmaxf(v0, v1));
    float s = wave_sum(__expf(v0 - m) + __expf(v1 - m));
    if (l == 0) zres[b] = m + __logf(s) - pathf[b] - pathb[b];
}

// ---------------------------------------------------------------------------
// mean_kernel: 1 wave. out = mean(zres). 8 values/lane (2x float4) + DPP tree.
// ---------------------------------------------------------------------------
__global__ __launch_bounds__(64) void mean_kernel(
    const float* __restrict__ zres, float* __restrict__ out)
{
    const int l = threadIdx.x;
    const float4* z4 = (const float4*)zres;
    float4 a = z4[2 * l];
    float4 c = z4[2 * l + 1];
    float acc = ((a.x + a.y) + (a.z + a.w)) + ((c.x + c.y) + (c.z + c.w));
    acc = wave_sum(acc);
    if (l == 0) out[0] = acc * (1.0f / (float)B_);
}

// ---------------------------------------------------------------------------
extern "C" void kernel_launch(void* const* d_in, const int* in_sizes, int n_in,
                              void* d_out, int out_size, void* d_ws, size_t ws_size,
                              hipStream_t stream) {
    const float* emission    = (const float*)d_in[0];
    const int*   target      = (const int*)  d_in[1];
    const float* mask        = (const float*)d_in[2];
    const float* start_trans = (const float*)d_in[3];
    const float* trans       = (const float*)d_in[4];
    float* out = (float*)d_out;

    float* ws_f  = (float*)d_ws;
    float* alpha = ws_f;                        // 512*128
    float* beta  = ws_f + B_ * N_;              // 512*128
    float* pathf = ws_f + 2 * B_ * N_;          // 512
    float* pathb = ws_f + 2 * B_ * N_ + B_;     // 512
    float* zres  = ws_f + 2 * B_ * N_ + 2 * B_; // 512

    norm_kernel<<<2 * B_, 64, 0, stream>>>(emission, target, mask, start_trans,
                                           trans, alpha, beta, pathf, pathb);
    zres_kernel<<<B_, 64, 0, stream>>>(alpha, beta, pathf, pathb, zres);
    mean_kernel<<<1, 64, 0, stream>>>(zres, out);
}